// Round 10
// baseline (1060.467 us; speedup 1.0000x reference)
//
#include <hip/hip_runtime.h>

typedef __attribute__((ext_vector_type(8))) short short8;   // 8 bf16
typedef __attribute__((ext_vector_type(4))) float f32x4;    // MFMA acc

__device__ __forceinline__ unsigned short bf16r(float f) {
  unsigned int u = __float_as_uint(f);
  u = (u + 0x7FFFu + ((u >> 16) & 1u)) >> 16;
  return (unsigned short)u;
}
__device__ __forceinline__ float bf2f(unsigned short h) {
  return __uint_as_float(((unsigned int)h) << 16);
}
__device__ __forceinline__ unsigned int pk2(float a, float b) {
  return (unsigned int)bf16r(a) | ((unsigned int)bf16r(b) << 16);
}

// async 16B global->LDS (dest is wave-uniform base + lane*16)
__device__ __forceinline__ void gload16(const unsigned short* g, unsigned short* l) {
  __builtin_amdgcn_global_load_lds(
      (const __attribute__((address_space(1))) unsigned int*)g,
      (__attribute__((address_space(3))) unsigned int*)l, 16, 0, 0);
}

// Stage a 128x32 bf16 tile (8KB) into LDS, XOR-swizzled chunks.
__device__ __forceinline__ void stage_tile(const unsigned short* __restrict__ gsrc, int ld,
                                           int k0, unsigned short* Ls, int t) {
  const int w = t >> 6;
  const int o0 = t * 16;
  const int r0 = o0 >> 6;
  const int c0 = ((((o0 >> 4) & 3) ^ ((r0 >> 2) & 3)) << 3);
  const int r1 = r0 + 64;
  const int c1 = ((((o0 >> 4) & 3) ^ ((r1 >> 2) & 3)) << 3);
  gload16(gsrc + (long)r0 * ld + k0 + c0, Ls + w * 512);
  gload16(gsrc + (long)r1 * ld + k0 + c1, Ls + 2048 + w * 512);
}

// Double-buffered LDS K-loop (2-phase), 128x128 tile, 4 waves, 4x4 frags.
__device__ __forceinline__ void kloop(const unsigned short* __restrict__ A,
                                      const unsigned short* __restrict__ B,
                                      int lda, int ldb, int K,
                                      unsigned short* As, unsigned short* Bs,  // [2][4096]
                                      int t, f32x4 acc[4][4]) {
  const int lane = t & 63;
  const int w = t >> 6;
  const int wr = w >> 1, wc = w & 1;
  const int ra = lane & 15;
  const int ch = ((lane >> 4) ^ (ra >> 2)) << 3;
  stage_tile(A, lda, 0, As, t);
  stage_tile(B, ldb, 0, Bs, t);
  __syncthreads();
  for (int k0 = 0; k0 < K; k0 += 32) {
    const int p = (k0 >> 5) & 1;
    unsigned short* Ac = As + p * 4096;
    unsigned short* Bc = Bs + p * 4096;
    if (k0 + 32 < K) {
      stage_tile(A, lda, k0 + 32, As + (p ^ 1) * 4096, t);
      stage_tile(B, ldb, k0 + 32, Bs + (p ^ 1) * 4096, t);
    }
    short8 a[4], b[4];
#pragma unroll
    for (int i = 0; i < 4; ++i)
      a[i] = *(const short8*)(Ac + (wr * 64 + i * 16 + ra) * 32 + ch);
#pragma unroll
    for (int j = 0; j < 4; ++j)
      b[j] = *(const short8*)(Bc + (wc * 64 + j * 16 + ra) * 32 + ch);
#pragma unroll
    for (int i = 0; i < 4; ++i)
#pragma unroll
      for (int j = 0; j < 4; ++j)
        acc[i][j] = __builtin_amdgcn_mfma_f32_16x16x32_bf16(b[j], a[i], acc[i][j], 0, 0, 0);
    __syncthreads();
  }
}

// ---------------- fused fp32->bf16 convert of all inputs ----------------
__global__ __launch_bounds__(256)
void cvt_all(const float* __restrict__ ref, const float* __restrict__ sup,
             const float* __restrict__ fcw, const float* __restrict__ wq,
             const float* __restrict__ wk, const float* __restrict__ wv,
             unsigned short* __restrict__ Xb, unsigned short* __restrict__ FCW,
             unsigned short* __restrict__ WQB, unsigned short* __restrict__ WKB,
             unsigned short* __restrict__ WVB) {
  long u = ((long)blockIdx.x * 256 + threadIdx.x) * 4;
  const float* src; unsigned short* dst;
  if (u < 2097152)      { src = ref + u;             dst = Xb + u; }
  else if (u < 3145728) { src = sup + (u - 2097152); dst = Xb + u; }
  else if (u < 4194304) { src = fcw + (u - 3145728); dst = FCW + (u - 3145728); }
  else if (u < 5242880) { src = wq + (u - 4194304);  dst = WQB + (u - 4194304); }
  else if (u < 6291456) { src = wk + (u - 5242880);  dst = WKB + (u - 5242880); }
  else                  { src = wv + (u - 6291456);  dst = WVB + (u - 6291456); }
  float4 v = *(const float4*)src;
  ushort4 o;
  o.x = bf16r(v.x); o.y = bf16r(v.y); o.z = bf16r(v.z); o.w = bf16r(v.w);
  *(ushort4*)dst = o;
}

// ---------------- fc: RS = relu(X @ fcW^T + b), bf16 out ----------------
__global__ __launch_bounds__(256)
void gemm_fc(const unsigned short* __restrict__ X, const unsigned short* __restrict__ W,
             const float* __restrict__ bias, unsigned short* __restrict__ RS) {
  __shared__ unsigned short As[8192], Bs[8192];
  const int t = threadIdx.x, lane = t & 63, w = t >> 6;
  const int wr = w >> 1, wc = w & 1;
  const int row0 = blockIdx.x * 128, col0 = blockIdx.y * 128;
  f32x4 acc[4][4] = {};
  kloop(X + (long)row0 * 1024, W + (long)col0 * 1024, 1024, 1024, 1024, As, Bs, t, acc);
  const int rl = lane & 15, q4 = (lane >> 4) << 2;
#pragma unroll
  for (int i = 0; i < 4; ++i) {
    int rr = row0 + wr * 64 + i * 16 + rl;
#pragma unroll
    for (int j = 0; j < 4; ++j) {
      int cc = col0 + wc * 64 + j * 16 + q4;
      float4 bb = *(const float4*)(bias + cc);
      float v0 = fmaxf(acc[i][j][0] + bb.x, 0.f);
      float v1 = fmaxf(acc[i][j][1] + bb.y, 0.f);
      float v2 = fmaxf(acc[i][j][2] + bb.z, 0.f);
      float v3 = fmaxf(acc[i][j][3] + bb.w, 0.f);
      uint2 o; o.x = pk2(v0, v1); o.y = pk2(v2, v3);
      *(uint2*)(RS + (long)rr * 1024 + cc) = o;
    }
  }
}

// ---------------- batched Q/K/SV: z=0 Q(*C2), z=1 K, z=2 SV^T ----------------
__global__ __launch_bounds__(256)
void gemm_qkv(const unsigned short* __restrict__ RS,
              const unsigned short* __restrict__ WQ, const unsigned short* __restrict__ WK,
              const unsigned short* __restrict__ WV,
              const float* __restrict__ qb, const float* __restrict__ kb,
              unsigned short* __restrict__ QG, unsigned short* __restrict__ KG,
              unsigned short* __restrict__ SVT) {
  const int z = blockIdx.z;
  const unsigned short* A; const unsigned short* B; int M;
  if (z == 0)      { A = RS;           B = WQ; M = 2048; }
  else if (z == 1) { A = RS + 2097152; B = WK; M = 1024; }
  else             { A = RS + 2097152; B = WV; M = 1024; }
  const int row0 = blockIdx.x * 128;
  if (row0 >= M) return;
  const int col0 = blockIdx.y * 128;
  __shared__ unsigned short As[8192], Bs[8192];
  const int t = threadIdx.x, lane = t & 63, w = t >> 6;
  const int wr = w >> 1, wc = w & 1;
  f32x4 acc[4][4] = {};
  kloop(A + (long)row0 * 1024, B + (long)col0 * 1024, 1024, 1024, 1024, As, Bs, t, acc);
  const int rl = lane & 15, q4 = (lane >> 4) << 2;
  if (z == 2) {
#pragma unroll
    for (int i = 0; i < 4; ++i) {
      int rr = row0 + wr * 64 + i * 16 + rl;           // sup row = SVT col
#pragma unroll
      for (int j = 0; j < 4; ++j) {
        int cg = col0 + wc * 64 + j * 16 + q4;         // output channel
#pragma unroll
        for (int ri = 0; ri < 4; ++ri) {
          int gg = (cg + ri) >> 6, jj = (cg + ri) & 63;
          SVT[(long)gg * 65536 + (long)jj * 1024 + rr] = bf16r(acc[i][j][ri]);
        }
      }
    }
  } else {
    const float* bias = z ? kb : qb;
    unsigned short* out = z ? KG : QG;
    const long gs = z ? 65536 : 131072;
    const float scl = z ? 1.0f : 0.18033688011112042f;   // fold log2(e)/8 into Q
#pragma unroll
    for (int i = 0; i < 4; ++i) {
      int rr = row0 + wr * 64 + i * 16 + rl;
#pragma unroll
      for (int j = 0; j < 4; ++j) {
        int cc = col0 + wc * 64 + j * 16 + q4;
        float4 bb = *(const float4*)(bias + cc);
        int gg = cc >> 6, jj = cc & 63;
        uint2 o;
        o.x = pk2((acc[i][j][0] + bb.x) * scl, (acc[i][j][1] + bb.y) * scl);
        o.y = pk2((acc[i][j][2] + bb.z) * scl, (acc[i][j][3] + bb.w) * scl);
        *(uint2*)(out + (long)gg * gs + (long)rr * 64 + jj) = o;
      }
    }
  }
}

// ------- fused conv(E->G) + scores + partial softmax + PV (m-split x4) -----
// Grid (128, 4): block = 16 n x 256 m, 8 waves, wave w owns groups {2w,2w+1}.
// Conv accumulated in PER-THREAD REGISTERS; pe loaded via an EXPLICIT 4-slot
// software pipeline over e (named static slots, 12-16 loads in flight/thread).
// No block barriers in the main loop. Per chunk the conv quads round-trip a
// wave-private swizzled LDS buffer to reach the scores-MFMA C-layout; scores/
// softmax/PV identical to the validated r7 code. Writes unnormalized partials.
__global__ __launch_bounds__(512)
void pe_attn4(const float* __restrict__ pe, const float* __restrict__ wgw,
              const float* __restrict__ wgb,
              const unsigned short* __restrict__ QG,
              const unsigned short* __restrict__ KG,
              const unsigned short* __restrict__ SVT,
              float* __restrict__ Opart, float* __restrict__ ms)
{
  __shared__ float wgs[1024];                            // [64e][16g]
  __shared__ __align__(16) float Lw[8][1024];            // per-wave [16n][64m] f32, swz
  __shared__ __align__(16) unsigned char Ps[8][2048];    // per-wave P bf16, swz

  const int t = threadIdx.x;
  const int lane = t & 63;
  const int w = t >> 6;
  const int rl = lane & 15;
  const int hi = lane >> 4;
  const int n0 = blockIdx.x * 16;
  const int sp = blockIdx.y;           // m-split 0..3
  const int g0 = w * 2;

  for (int i = t; i < 1024; i += 512) wgs[(i & 63) * 16 + (i >> 6)] = wgw[i];
  __syncthreads();                     // the only block barrier

  // Q fragments (QG already scaled by log2(e)/8)
  short8 qf0k0 = *(const short8*)(QG + (long)g0 * 131072 + (long)(n0 + rl) * 64 + hi * 8);
  short8 qf0k1 = *(const short8*)(QG + (long)g0 * 131072 + (long)(n0 + rl) * 64 + 32 + hi * 8);
  short8 qf1k0 = *(const short8*)(QG + (long)(g0 + 1) * 131072 + (long)(n0 + rl) * 64 + hi * 8);
  short8 qf1k1 = *(const short8*)(QG + (long)(g0 + 1) * 131072 + (long)(n0 + rl) * 64 + 32 + hi * 8);

  f32x4 Oa[2][4] = {};
  float mx0 = -1e30f, mx1 = -1e30f, sm0 = 0.f, sm1 = 0.f;
  const float bias0 = wgb[g0], bias1 = wgb[g0 + 1];
  float* Lww = Lw[w];
  unsigned char* Pw = Ps[w];
  const int qmsk = (rl & 7) << 4;
  const int rx = rl & 7;

  for (int chunk = 0; chunk < 4; ++chunk) {
    const int m0c = sp * 256 + chunk * 64;
    f32x4 c0[4], c1[4];
#pragma unroll
    for (int q = 0; q < 4; ++q) {
      c0[q] = (f32x4){bias0, bias0, bias0, bias0};
      c1[q] = (f32x4){bias1, bias1, bias1, bias1};
    }
    const float* pb = pe + (long)(n0 + rl) * 1024 + m0c + hi * 16;

    // ---- conv over E: explicit 4-slot software pipeline ----
    f32x4 s0a, s0b, s0c, s0d, s1a, s1b, s1c, s1d;
    f32x4 s2a, s2b, s2c, s2d, s3a, s3b, s3c, s3d;
#define LOADP(S, E)                                                           \
  do {                                                                        \
    const f32x4* _p = (const f32x4*)(pb + (long)(E) * 2097152);               \
    s##S##a = _p[0]; s##S##b = _p[1]; s##S##c = _p[2]; s##S##d = _p[3];       \
  } while (0)
#define FMAE(S, E)                                                            \
  do {                                                                        \
    float2 wg2_ = *(const float2*)(wgs + (E) * 16 + g0);                      \
    c0[0] += s##S##a * wg2_.x; c0[1] += s##S##b * wg2_.x;                     \
    c0[2] += s##S##c * wg2_.x; c0[3] += s##S##d * wg2_.x;                     \
    c1[0] += s##S##a * wg2_.y; c1[1] += s##S##b * wg2_.y;                     \
    c1[2] += s##S##c * wg2_.y; c1[3] += s##S##d * wg2_.y;                     \
  } while (0)
    LOADP(0, 0);
    LOADP(1, 1);
    LOADP(2, 2);
    for (int eb = 0; eb < 64; eb += 4) {
      if (eb + 3 < 64) LOADP(3, eb + 3);
      FMAE(0, eb);
      if (eb + 4 < 64) LOADP(0, eb + 4);
      FMAE(1, eb + 1);
      if (eb + 5 < 64) LOADP(1, eb + 5);
      FMAE(2, eb + 2);
      if (eb + 6 < 64) LOADP(2, eb + 6);
      FMAE(3, eb + 3);
    }
#undef LOADP
#undef FMAE

    // ---- per-group: relayout via wave-private LDS, scores, softmax, PV ----
#pragma unroll
    for (int gi = 0; gi < 2; ++gi) {
      const int g = g0 + gi;
#pragma unroll
      for (int q = 0; q < 4; ++q)
        *(f32x4*)(Lww + rl * 64 + ((((hi << 2) + q) ^ rx) << 2)) = gi ? c1[q] : c0[q];
      f32x4 sa[4];
#pragma unroll
      for (int mb = 0; mb < 4; ++mb) {
        const long krow = (long)g * 65536 + (long)(m0c + mb * 16 + rl) * 64 + hi * 8;
        short8 ka = *(const short8*)(KG + krow);
        short8 kb2 = *(const short8*)(KG + krow + 32);
        f32x4 z = {};
        z = __builtin_amdgcn_mfma_f32_16x16x32_bf16(ka, gi ? qf1k0 : qf0k0, z, 0, 0, 0);
        z = __builtin_amdgcn_mfma_f32_16x16x32_bf16(kb2, gi ? qf1k1 : qf0k1, z, 0, 0, 0);
        sa[mb] = z;
      }
      float wv[4][4];
      float cmax = -1e30f;
#pragma unroll
      for (int mb = 0; mb < 4; ++mb) {
        f32x4 cv = *(const f32x4*)(Lww + rl * 64 + ((((mb << 2) + hi) ^ rx) << 2));
#pragma unroll
        for (int ri = 0; ri < 4; ++ri) {
          float v = __builtin_amdgcn_logf(fmaxf(cv[ri], 0.f) + 1e-6f) + sa[mb][ri];
          wv[mb][ri] = v;
          cmax = fmaxf(cmax, v);
        }
      }
      cmax = fmaxf(cmax, __shfl_xor(cmax, 16));
      cmax = fmaxf(cmax, __shfl_xor(cmax, 32));
      float oldm = gi ? mx1 : mx0;
      float newm = fmaxf(oldm, cmax);
      float scale = __builtin_amdgcn_exp2f(oldm - newm);
      float csum = 0.f;
      float pv[4][4];
#pragma unroll
      for (int mb = 0; mb < 4; ++mb)
#pragma unroll
        for (int ri = 0; ri < 4; ++ri) {
          float p = __builtin_amdgcn_exp2f(wv[mb][ri] - newm);
          pv[mb][ri] = p;
          csum += p;
        }
      csum += __shfl_xor(csum, 16);
      csum += __shfl_xor(csum, 32);
      if (gi) { mx1 = newm; sm1 = sm1 * scale + csum; }
      else    { mx0 = newm; sm0 = sm0 * scale + csum; }
#pragma unroll
      for (int jb = 0; jb < 4; ++jb) Oa[gi][jb] *= scale;
#pragma unroll
      for (int mb = 0; mb < 4; ++mb) {
        uint2 o;
        o.x = pk2(pv[mb][0], pv[mb][1]);
        o.y = pk2(pv[mb][2], pv[mb][3]);
        *(uint2*)(Pw + ((rl * 128 + mb * 32 + hi * 8) ^ qmsk)) = o;
      }
#pragma unroll
      for (int jb = 0; jb < 4; ++jb) {
#pragma unroll
        for (int mc = 0; mc < 2; ++mc) {
          short8 sv = *(const short8*)(SVT + (long)g * 65536 +
                                       (long)(jb * 16 + rl) * 1024 + m0c + mc * 32 + hi * 8);
          short8 pf = *(const short8*)(Pw + ((rl * 128 + mc * 64 + hi * 16) ^ qmsk));
          Oa[gi][jb] = __builtin_amdgcn_mfma_f32_16x16x32_bf16(sv, pf, Oa[gi][jb], 0, 0, 0);
        }
      }
    }
  }
  // ---- write partials: Opart[sp][n][g*64+d] (unnormalized), ms[sp][n][g] ----
  const int n = n0 + rl;
#pragma unroll
  for (int gi = 0; gi < 2; ++gi) {
    if (hi == 0) {
      float2 v; v.x = gi ? mx1 : mx0; v.y = gi ? sm1 : sm0;
      *(float2*)(ms + (((long)sp * 2048 + n) * 16 + g0 + gi) * 2) = v;
    }
#pragma unroll
    for (int jb = 0; jb < 4; ++jb) {
      *(f32x4*)(Opart + ((long)sp * 2048 + n) * 1024 + (g0 + gi) * 64 + jb * 16 + hi * 4) =
          Oa[gi][jb];
    }
  }
}

// ---------------- combine 4 m-splits + epilogue: out = O/S + wv_b + R --------
__global__ __launch_bounds__(256)
void combine(const float* __restrict__ Opart, const float* __restrict__ ms,
             const unsigned short* __restrict__ RS, const float* __restrict__ wvb,
             float* __restrict__ out) {
  const int n = blockIdx.x;
  const int t = threadIdx.x;
  const int g = t >> 4;
  float mv0, mv1, mv2, mv3, sv0, sv1, sv2, sv3;
  {
    float2 a = *(const float2*)(ms + (((long)0 * 2048 + n) * 16 + g) * 2);
    float2 b = *(const float2*)(ms + (((long)1 * 2048 + n) * 16 + g) * 2);
    float2 c = *(const float2*)(ms + (((long)2 * 2048 + n) * 16 + g) * 2);
    float2 d = *(const float2*)(ms + (((long)3 * 2048 + n) * 16 + g) * 2);
    mv0 = a.x; sv0 = a.y; mv1 = b.x; sv1 = b.y;
    mv2 = c.x; sv2 = c.y; mv3 = d.x; sv3 = d.y;
  }
  float M = fmaxf(fmaxf(mv0, mv1), fmaxf(mv2, mv3));
  float w0 = __builtin_amdgcn_exp2f(mv0 - M);
  float w1 = __builtin_amdgcn_exp2f(mv1 - M);
  float w2 = __builtin_amdgcn_exp2f(mv2 - M);
  float w3 = __builtin_amdgcn_exp2f(mv3 - M);
  float S = sv0 * w0 + sv1 * w1 + sv2 * w2 + sv3 * w3;
  f32x4 acc;
  acc  = (*(const f32x4*)(Opart + ((long)0 * 2048 + n) * 1024 + t * 4)) * w0;
  acc += (*(const f32x4*)(Opart + ((long)1 * 2048 + n) * 1024 + t * 4)) * w1;
  acc += (*(const f32x4*)(Opart + ((long)2 * 2048 + n) * 1024 + t * 4)) * w2;
  acc += (*(const f32x4*)(Opart + ((long)3 * 2048 + n) * 1024 + t * 4)) * w3;
  float rs = __builtin_amdgcn_rcpf(S);
  const int oc = t * 4;
  float4 wb = *(const float4*)(wvb + oc);
  ushort4 r4 = *(const ushort4*)(RS + (long)n * 1024 + oc);
  float4 o;
  o.x = acc[0] * rs + wb.x + bf2f(r4.x);
  o.y = acc[1] * rs + wb.y + bf2f(r4.y);
  o.z = acc[2] * rs + wb.z + bf2f(r4.z);
  o.w = acc[3] * rs + wb.w + bf2f(r4.w);
  *(float4*)(out + (long)n * 1024 + oc) = o;
}

extern "C" void kernel_launch(void* const* d_in, const int* in_sizes, int n_in,
                              void* d_out, int out_size, void* d_ws, size_t ws_size,
                              hipStream_t stream) {
  const float* ref_feat = (const float*)d_in[0];
  const float* sup_feat = (const float*)d_in[1];
  const float* pe       = (const float*)d_in[2];
  const float* fc_w     = (const float*)d_in[3];
  const float* fc_b     = (const float*)d_in[4];
  const float* wg_w     = (const float*)d_in[5];
  const float* wg_b     = (const float*)d_in[6];
  const float* wq_w     = (const float*)d_in[7];
  const float* wq_b     = (const float*)d_in[8];
  const float* wk_w     = (const float*)d_in[9];
  const float* wk_b     = (const float*)d_in[10];
  const float* wv_w     = (const float*)d_in[11];
  const float* wv_b     = (const float*)d_in[12];

  char* ws = (char*)d_ws;
  unsigned short* Xb  = (unsigned short*)(ws);              // [3072][1024]
  unsigned short* FCW = (unsigned short*)(ws + 6291456);
  unsigned short* WQB = (unsigned short*)(ws + 8388608);
  unsigned short* WKB = (unsigned short*)(ws + 10485760);
  unsigned short* WVB = (unsigned short*)(ws + 12582912);
  unsigned short* RS  = (unsigned short*)(ws + 14680064);   // [3072][1024] relu(fc) bf16
  unsigned short* QG  = (unsigned short*)(ws + 20971520);   // [16][2048][64] (Q * log2e/8)
  unsigned short* KG  = (unsigned short*)(ws + 25165824);   // [16][1024][64]
  unsigned short* SVT = (unsigned short*)(ws + 27262976);   // [16][64][1024]
  float*          Opart = (float*)(ws + 29360128);          // [4][2048][1024] f32
  float*          msb   = (float*)(ws + 62914560);          // [4][2048][16][2] f32

  cvt_all<<<7168, 256, 0, stream>>>(ref_feat, sup_feat, fc_w, wq_w, wk_w, wv_w,
                                    Xb, FCW, WQB, WKB, WVB);
  gemm_fc<<<dim3(24, 8), 256, 0, stream>>>(Xb, FCW, fc_b, RS);
  gemm_qkv<<<dim3(16, 8, 3), 256, 0, stream>>>(RS, WQB, WKB, WVB, wq_b, wk_b, QG, KG, SVT);
  pe_attn4<<<dim3(128, 4), 512, 0, stream>>>(pe, wg_w, wg_b, QG, KG, SVT, Opart, msb);
  combine<<<2048, 256, 0, stream>>>(Opart, msb, RS, wv_b, (float*)d_out);
}

// Round 11
// 294.348 us; speedup vs baseline: 3.6028x; 3.6028x over previous
//
#include <hip/hip_runtime.h>

typedef __attribute__((ext_vector_type(8))) short short8;   // 8 bf16
typedef __attribute__((ext_vector_type(4))) float f32x4;    // MFMA acc

__device__ __forceinline__ unsigned short bf16r(float f) {
  unsigned int u = __float_as_uint(f);
  u = (u + 0x7FFFu + ((u >> 16) & 1u)) >> 16;
  return (unsigned short)u;
}
__device__ __forceinline__ float bf2f(unsigned short h) {
  return __uint_as_float(((unsigned int)h) << 16);
}
__device__ __forceinline__ unsigned int pk2(float a, float b) {
  return (unsigned int)bf16r(a) | ((unsigned int)bf16r(b) << 16);
}

// async 16B global->LDS (dest is wave-uniform base + lane*16)
__device__ __forceinline__ void gload16(const unsigned short* g, unsigned short* l) {
  __builtin_amdgcn_global_load_lds(
      (const __attribute__((address_space(1))) unsigned int*)g,
      (__attribute__((address_space(3))) unsigned int*)l, 16, 0, 0);
}

// Stage a 128x32 bf16 tile (8KB) into LDS, XOR-swizzled chunks.
__device__ __forceinline__ void stage_tile(const unsigned short* __restrict__ gsrc, int ld,
                                           int k0, unsigned short* Ls, int t) {
  const int w = t >> 6;
  const int o0 = t * 16;
  const int r0 = o0 >> 6;
  const int c0 = ((((o0 >> 4) & 3) ^ ((r0 >> 2) & 3)) << 3);
  const int r1 = r0 + 64;
  const int c1 = ((((o0 >> 4) & 3) ^ ((r1 >> 2) & 3)) << 3);
  gload16(gsrc + (long)r0 * ld + k0 + c0, Ls + w * 512);
  gload16(gsrc + (long)r1 * ld + k0 + c1, Ls + 2048 + w * 512);
}

// Double-buffered LDS K-loop (2-phase), 128x128 tile, 4 waves, 4x4 frags.
__device__ __forceinline__ void kloop(const unsigned short* __restrict__ A,
                                      const unsigned short* __restrict__ B,
                                      int lda, int ldb, int K,
                                      unsigned short* As, unsigned short* Bs,  // [2][4096]
                                      int t, f32x4 acc[4][4]) {
  const int lane = t & 63;
  const int w = t >> 6;
  const int wr = w >> 1, wc = w & 1;
  const int ra = lane & 15;
  const int ch = ((lane >> 4) ^ (ra >> 2)) << 3;
  stage_tile(A, lda, 0, As, t);
  stage_tile(B, ldb, 0, Bs, t);
  __syncthreads();
  for (int k0 = 0; k0 < K; k0 += 32) {
    const int p = (k0 >> 5) & 1;
    unsigned short* Ac = As + p * 4096;
    unsigned short* Bc = Bs + p * 4096;
    if (k0 + 32 < K) {
      stage_tile(A, lda, k0 + 32, As + (p ^ 1) * 4096, t);
      stage_tile(B, ldb, k0 + 32, Bs + (p ^ 1) * 4096, t);
    }
    short8 a[4], b[4];
#pragma unroll
    for (int i = 0; i < 4; ++i)
      a[i] = *(const short8*)(Ac + (wr * 64 + i * 16 + ra) * 32 + ch);
#pragma unroll
    for (int j = 0; j < 4; ++j)
      b[j] = *(const short8*)(Bc + (wc * 64 + j * 16 + ra) * 32 + ch);
#pragma unroll
    for (int i = 0; i < 4; ++i)
#pragma unroll
      for (int j = 0; j < 4; ++j)
        acc[i][j] = __builtin_amdgcn_mfma_f32_16x16x32_bf16(b[j], a[i], acc[i][j], 0, 0, 0);
    __syncthreads();
  }
}

// ---------------- fused fp32->bf16 convert of all inputs ----------------
__global__ __launch_bounds__(256)
void cvt_all(const float* __restrict__ ref, const float* __restrict__ sup,
             const float* __restrict__ fcw, const float* __restrict__ wq,
             const float* __restrict__ wk, const float* __restrict__ wv,
             unsigned short* __restrict__ Xb, unsigned short* __restrict__ FCW,
             unsigned short* __restrict__ WQB, unsigned short* __restrict__ WKB,
             unsigned short* __restrict__ WVB) {
  long u = ((long)blockIdx.x * 256 + threadIdx.x) * 4;
  const float* src; unsigned short* dst;
  if (u < 2097152)      { src = ref + u;             dst = Xb + u; }
  else if (u < 3145728) { src = sup + (u - 2097152); dst = Xb + u; }
  else if (u < 4194304) { src = fcw + (u - 3145728); dst = FCW + (u - 3145728); }
  else if (u < 5242880) { src = wq + (u - 4194304);  dst = WQB + (u - 4194304); }
  else if (u < 6291456) { src = wk + (u - 5242880);  dst = WKB + (u - 5242880); }
  else                  { src = wv + (u - 6291456);  dst = WVB + (u - 6291456); }
  float4 v = *(const float4*)src;
  ushort4 o;
  o.x = bf16r(v.x); o.y = bf16r(v.y); o.z = bf16r(v.z); o.w = bf16r(v.w);
  *(ushort4*)dst = o;
}

// ---------------- fc: RS = relu(X @ fcW^T + b), bf16 out ----------------
__global__ __launch_bounds__(256)
void gemm_fc(const unsigned short* __restrict__ X, const unsigned short* __restrict__ W,
             const float* __restrict__ bias, unsigned short* __restrict__ RS) {
  __shared__ unsigned short As[8192], Bs[8192];
  const int t = threadIdx.x, lane = t & 63, w = t >> 6;
  const int wr = w >> 1, wc = w & 1;
  const int row0 = blockIdx.x * 128, col0 = blockIdx.y * 128;
  f32x4 acc[4][4] = {};
  kloop(X + (long)row0 * 1024, W + (long)col0 * 1024, 1024, 1024, 1024, As, Bs, t, acc);
  const int rl = lane & 15, q4 = (lane >> 4) << 2;
#pragma unroll
  for (int i = 0; i < 4; ++i) {
    int rr = row0 + wr * 64 + i * 16 + rl;
#pragma unroll
    for (int j = 0; j < 4; ++j) {
      int cc = col0 + wc * 64 + j * 16 + q4;
      float4 bb = *(const float4*)(bias + cc);
      float v0 = fmaxf(acc[i][j][0] + bb.x, 0.f);
      float v1 = fmaxf(acc[i][j][1] + bb.y, 0.f);
      float v2 = fmaxf(acc[i][j][2] + bb.z, 0.f);
      float v3 = fmaxf(acc[i][j][3] + bb.w, 0.f);
      uint2 o; o.x = pk2(v0, v1); o.y = pk2(v2, v3);
      *(uint2*)(RS + (long)rr * 1024 + cc) = o;
    }
  }
}

// ---------------- batched Q/K/SV: z=0 Q, z=1 K, z=2 SV^T ----------------
__global__ __launch_bounds__(256)
void gemm_qkv(const unsigned short* __restrict__ RS,
              const unsigned short* __restrict__ WQ, const unsigned short* __restrict__ WK,
              const unsigned short* __restrict__ WV,
              const float* __restrict__ qb, const float* __restrict__ kb,
              unsigned short* __restrict__ QG, unsigned short* __restrict__ KG,
              unsigned short* __restrict__ SVT) {
  const int z = blockIdx.z;
  const unsigned short* A; const unsigned short* B; int M;
  if (z == 0)      { A = RS;           B = WQ; M = 2048; }
  else if (z == 1) { A = RS + 2097152; B = WK; M = 1024; }
  else             { A = RS + 2097152; B = WV; M = 1024; }
  const int row0 = blockIdx.x * 128;
  if (row0 >= M) return;
  const int col0 = blockIdx.y * 128;
  __shared__ unsigned short As[8192], Bs[8192];
  const int t = threadIdx.x, lane = t & 63, w = t >> 6;
  const int wr = w >> 1, wc = w & 1;
  f32x4 acc[4][4] = {};
  kloop(A + (long)row0 * 1024, B + (long)col0 * 1024, 1024, 1024, 1024, As, Bs, t, acc);
  const int rl = lane & 15, q4 = (lane >> 4) << 2;
  if (z == 2) {
#pragma unroll
    for (int i = 0; i < 4; ++i) {
      int rr = row0 + wr * 64 + i * 16 + rl;           // sup row = SVT col
#pragma unroll
      for (int j = 0; j < 4; ++j) {
        int cg = col0 + wc * 64 + j * 16 + q4;         // output channel
#pragma unroll
        for (int ri = 0; ri < 4; ++ri) {
          int gg = (cg + ri) >> 6, jj = (cg + ri) & 63;
          SVT[(long)gg * 65536 + (long)jj * 1024 + rr] = bf16r(acc[i][j][ri]);
        }
      }
    }
  } else {
    const float* bias = z ? kb : qb;
    unsigned short* out = z ? KG : QG;
    const long gs = z ? 65536 : 131072;
#pragma unroll
    for (int i = 0; i < 4; ++i) {
      int rr = row0 + wr * 64 + i * 16 + rl;
#pragma unroll
      for (int j = 0; j < 4; ++j) {
        int cc = col0 + wc * 64 + j * 16 + q4;
        float4 bb = *(const float4*)(bias + cc);
        int gg = cc >> 6, jj = cc & 63;
        uint2 o;
        o.x = pk2(acc[i][j][0] + bb.x, acc[i][j][1] + bb.y);
        o.y = pk2(acc[i][j][2] + bb.z, acc[i][j][3] + bb.w);
        *(uint2*)(out + (long)gg * gs + (long)rr * 64 + jj) = o;
      }
    }
  }
}

// ---------------- scores_g = (Q_g @ K_g^T) * log2(e)/8, bf16 ----------------
__global__ __launch_bounds__(256)
void gemm_scores(const unsigned short* __restrict__ QG, const unsigned short* __restrict__ KG,
                 unsigned short* __restrict__ SC) {
  const int g = blockIdx.z;
  const unsigned short* A = QG + (long)g * 131072;   // [2048][64]
  const unsigned short* B = KG + (long)g * 65536;    // [1024][64]
  const int t = threadIdx.x, lane = t & 63, w = t >> 6;
  const int wr = w >> 1, wc = w & 1;
  const int row0 = blockIdx.x * 128 + wr * 64, col0 = blockIdx.y * 128 + wc * 64;
  const int ra = lane & 15, kg8 = (lane >> 4) << 3;
  f32x4 acc[4][4] = {};
#pragma unroll
  for (int k0 = 0; k0 < 64; k0 += 32) {
    short8 a[4], b[4];
#pragma unroll
    for (int i = 0; i < 4; ++i)
      a[i] = *(const short8*)(A + (long)(row0 + i * 16 + ra) * 64 + k0 + kg8);
#pragma unroll
    for (int j = 0; j < 4; ++j)
      b[j] = *(const short8*)(B + (long)(col0 + j * 16 + ra) * 64 + k0 + kg8);
#pragma unroll
    for (int i = 0; i < 4; ++i)
#pragma unroll
      for (int j = 0; j < 4; ++j)
        acc[i][j] = __builtin_amdgcn_mfma_f32_16x16x32_bf16(b[j], a[i], acc[i][j], 0, 0, 0);
  }
  const int rl = lane & 15, q4 = (lane >> 4) << 2;
  const float s = 0.18033688011112042f;   // log2(e)/8
#pragma unroll
  for (int i = 0; i < 4; ++i) {
    int rr = row0 + i * 16 + rl;
#pragma unroll
    for (int j = 0; j < 4; ++j) {
      int cc = col0 + j * 16 + q4;
      uint2 o;
      o.x = pk2(acc[i][j][0] * s, acc[i][j][1] * s);
      o.y = pk2(acc[i][j][2] * s, acc[i][j][3] * s);
      *(uint2*)(SC + (long)g * 2097152 + (long)rr * 1024 + cc) = o;
    }
  }
}

// ---------------- fused position-bias conv + softmax (streams 512MB pe) ----
// 2048 blocks x 256 thr; thread t: m=4t..4t+3, all 16 g (acc[64]).
// 2-slot explicit prefetch (+8 VGPR only); exp2-in-place single pass.
__global__ __launch_bounds__(256)
void pe_softmax(const float* __restrict__ pe, const float* __restrict__ wgw,
                const float* __restrict__ wgb, unsigned short* __restrict__ Sc) {
  const int n = blockIdx.x;
  const int t = threadIdx.x;
  const int lane = t & 63;
  const int wid = t >> 6;
  __shared__ __align__(16) float wgT[64][16];
  __shared__ float redM[4][16];
  __shared__ float redS[4][16];
  for (int i = t; i < 1024; i += 256) wgT[i & 63][i >> 6] = wgw[i];
  __syncthreads();

  float acc[64];
#pragma unroll
  for (int g = 0; g < 16; ++g) {
    float bb = wgb[g];
#pragma unroll
    for (int mm = 0; mm < 4; ++mm) acc[g * 4 + mm] = bb;
  }

  const float* pebase = pe + (long)n * 1024 + t * 4;
  const long ES = 2097152;   // e-slice stride in floats
  float4 pb0 = *(const float4*)(pebase);
  float4 pb1 = *(const float4*)(pebase + ES);

#define FMA_E(ee, p)                                                          \
  do {                                                                        \
    const f32x4* wrow_ = (const f32x4*)(&wgT[ee][0]);                         \
    f32x4 w0_ = wrow_[0], w1_ = wrow_[1], w2_ = wrow_[2], w3_ = wrow_[3];     \
    float wg_[16] = {w0_[0], w0_[1], w0_[2], w0_[3], w1_[0], w1_[1], w1_[2],  \
                     w1_[3], w2_[0], w2_[1], w2_[2], w2_[3], w3_[0], w3_[1],  \
                     w3_[2], w3_[3]};                                         \
    _Pragma("unroll") for (int g = 0; g < 16; ++g) {                          \
      acc[g * 4 + 0] = fmaf(wg_[g], (p).x, acc[g * 4 + 0]);                   \
      acc[g * 4 + 1] = fmaf(wg_[g], (p).y, acc[g * 4 + 1]);                   \
      acc[g * 4 + 2] = fmaf(wg_[g], (p).z, acc[g * 4 + 2]);                   \
      acc[g * 4 + 3] = fmaf(wg_[g], (p).w, acc[g * 4 + 3]);                   \
    }                                                                         \
  } while (0)

  for (int e = 0; e < 62; e += 2) {
    float4 c0 = pb0; pb0 = *(const float4*)(pebase + (long)(e + 2) * ES);
    FMA_E(e + 0, c0);
    float4 c1 = pb1; pb1 = *(const float4*)(pebase + (long)(e + 3) * ES);
    FMA_E(e + 1, c1);
  }
  FMA_E(62, pb0);
  FMA_E(63, pb1);
#undef FMA_E

  // w = log2(relu(conv)+1e-6) + scores (scores pre-scaled by log2(e)/8)
#pragma unroll
  for (int g = 0; g < 16; ++g) {
    ushort4 s4 = *(const ushort4*)(Sc + (long)g * 2097152 + (long)n * 1024 + t * 4);
    acc[g * 4 + 0] = __builtin_amdgcn_logf(fmaxf(acc[g * 4 + 0], 0.f) + 1e-6f) + bf2f(s4.x);
    acc[g * 4 + 1] = __builtin_amdgcn_logf(fmaxf(acc[g * 4 + 1], 0.f) + 1e-6f) + bf2f(s4.y);
    acc[g * 4 + 2] = __builtin_amdgcn_logf(fmaxf(acc[g * 4 + 2], 0.f) + 1e-6f) + bf2f(s4.z);
    acc[g * 4 + 3] = __builtin_amdgcn_logf(fmaxf(acc[g * 4 + 3], 0.f) + 1e-6f) + bf2f(s4.w);
  }

  float gmax[16];
#pragma unroll
  for (int g = 0; g < 16; ++g) {
    float m = fmaxf(fmaxf(acc[g * 4 + 0], acc[g * 4 + 1]),
                    fmaxf(acc[g * 4 + 2], acc[g * 4 + 3]));
#pragma unroll
    for (int off = 32; off >= 1; off >>= 1) m = fmaxf(m, __shfl_xor(m, off));
    if (lane == 0) redM[wid][g] = m;
  }
  __syncthreads();
#pragma unroll
  for (int g = 0; g < 16; ++g)
    gmax[g] = fmaxf(fmaxf(redM[0][g], redM[1][g]), fmaxf(redM[2][g], redM[3][g]));

  // exp2 IN PLACE, then sum (single transcendental pass)
#pragma unroll
  for (int g = 0; g < 16; ++g) {
    acc[g * 4 + 0] = __builtin_amdgcn_exp2f(acc[g * 4 + 0] - gmax[g]);
    acc[g * 4 + 1] = __builtin_amdgcn_exp2f(acc[g * 4 + 1] - gmax[g]);
    acc[g * 4 + 2] = __builtin_amdgcn_exp2f(acc[g * 4 + 2] - gmax[g]);
    acc[g * 4 + 3] = __builtin_amdgcn_exp2f(acc[g * 4 + 3] - gmax[g]);
    float s = (acc[g * 4 + 0] + acc[g * 4 + 1]) + (acc[g * 4 + 2] + acc[g * 4 + 3]);
#pragma unroll
    for (int off = 32; off >= 1; off >>= 1) s += __shfl_xor(s, off);
    if (lane == 0) redS[wid][g] = s;
  }
  __syncthreads();

#pragma unroll
  for (int g = 0; g < 16; ++g) {
    float sum = redS[0][g] + redS[1][g] + redS[2][g] + redS[3][g];
    float rs = __builtin_amdgcn_rcpf(sum);
    ushort4 o;
    o.x = bf16r(acc[g * 4 + 0] * rs);
    o.y = bf16r(acc[g * 4 + 1] * rs);
    o.z = bf16r(acc[g * 4 + 2] * rs);
    o.w = bf16r(acc[g * 4 + 3] * rs);
    *(ushort4*)(Sc + (long)g * 2097152 + (long)n * 1024 + t * 4) = o;
  }
}

// ---------------- out = P_g @ SV_g^T + wv_b + R (fp32) ----------------
// Grid (32, 16) x 256 thr: block = 64 rows x one g; wave = 16 rows x 64 cols.
// Register-double-buffered K-loop, 4 MFMA + 5 loads per half-step.
__global__ __launch_bounds__(256)
void gemm_final(const unsigned short* __restrict__ SC, const unsigned short* __restrict__ SVT,
                const unsigned short* __restrict__ RS, const float* __restrict__ wvb,
                float* __restrict__ out) {
  const int g = blockIdx.y;
  const unsigned short* A = SC + (long)g * 2097152;  // [2048][1024]
  const unsigned short* B = SVT + (long)g * 65536;   // [64][1024]
  const int t = threadIdx.x, lane = t & 63, w = t >> 6;
  const int row0 = blockIdx.x * 64 + w * 16;
  const int ra = lane & 15, kg8 = (lane >> 4) << 3;
  f32x4 acc[4] = {};
  short8 a0, b0[4], a1, b1[4];

#define LDF(aa, bb, kk)                                                        \
  do {                                                                         \
    aa = *(const short8*)(A + (long)(row0 + ra) * 1024 + (kk) + kg8);          \
    _Pragma("unroll") for (int j = 0; j < 4; ++j)                              \
        bb[j] = *(const short8*)(B + (long)(j * 16 + ra) * 1024 + (kk) + kg8); \
  } while (0)
#define MM(aa, bb)                                                             \
  do {                                                                         \
    _Pragma("unroll") for (int j = 0; j < 4; ++j)                              \
      acc[j] = __builtin_amdgcn_mfma_f32_16x16x32_bf16(bb[j], aa, acc[j], 0, 0, 0); \
  } while (0)

  LDF(a0, b0, 0);
  for (int k0 = 0; k0 < 1024; k0 += 64) {
    LDF(a1, b1, k0 + 32);
    MM(a0, b0);
    if (k0 + 64 < 1024) LDF(a0, b0, k0 + 64);
    MM(a1, b1);
  }
#undef LDF
#undef MM

  const int rl = lane & 15, q4 = (lane >> 4) << 2;
  const int rr = row0 + rl;
#pragma unroll
  for (int j = 0; j < 4; ++j) {
    int oc = g * 64 + j * 16 + q4;
    float4 w4 = *(const float4*)(wvb + oc);
    ushort4 r4 = *(const ushort4*)(RS + (long)rr * 1024 + oc);
    float4 o;
    o.x = acc[j][0] + w4.x + bf2f(r4.x);
    o.y = acc[j][1] + w4.y + bf2f(r4.y);
    o.z = acc[j][2] + w4.z + bf2f(r4.z);
    o.w = acc[j][3] + w4.w + bf2f(r4.w);
    *(float4*)(out + (long)rr * 1024 + oc) = o;
  }
}

extern "C" void kernel_launch(void* const* d_in, const int* in_sizes, int n_in,
                              void* d_out, int out_size, void* d_ws, size_t ws_size,
                              hipStream_t stream) {
  const float* ref_feat = (const float*)d_in[0];
  const float* sup_feat = (const float*)d_in[1];
  const float* pe       = (const float*)d_in[2];
  const float* fc_w     = (const float*)d_in[3];
  const float* fc_b     = (const float*)d_in[4];
  const float* wg_w     = (const float*)d_in[5];
  const float* wg_b     = (const float*)d_in[6];
  const float* wq_w     = (const float*)d_in[7];
  const float* wq_b     = (const float*)d_in[8];
  const float* wk_w     = (const float*)d_in[9];
  const float* wk_b     = (const float*)d_in[10];
  const float* wv_w     = (const float*)d_in[11];
  const float* wv_b     = (const float*)d_in[12];

  char* ws = (char*)d_ws;
  unsigned short* Xb  = (unsigned short*)(ws);              // [3072][1024]
  unsigned short* FCW = (unsigned short*)(ws + 6291456);
  unsigned short* WQB = (unsigned short*)(ws + 8388608);
  unsigned short* WKB = (unsigned short*)(ws + 10485760);
  unsigned short* WVB = (unsigned short*)(ws + 12582912);
  unsigned short* RS  = (unsigned short*)(ws + 14680064);   // [3072][1024] relu(fc) bf16
  unsigned short* QG  = (unsigned short*)(ws + 20971520);   // [16][2048][64]
  unsigned short* KG  = (unsigned short*)(ws + 25165824);   // [16][1024][64]
  unsigned short* SVT = (unsigned short*)(ws + 27262976);   // [16][64][1024]
  unsigned short* SC  = (unsigned short*)(ws + 29360128);   // [16][2048][1024]

  cvt_all<<<7168, 256, 0, stream>>>(ref_feat, sup_feat, fc_w, wq_w, wk_w, wv_w,
                                    Xb, FCW, WQB, WKB, WVB);
  gemm_fc<<<dim3(24, 8), 256, 0, stream>>>(Xb, FCW, fc_b, RS);
  gemm_qkv<<<dim3(16, 8, 3), 256, 0, stream>>>(RS, WQB, WKB, WVB, wq_b, wk_b, QG, KG, SVT);
  gemm_scores<<<dim3(16, 8, 16), 256, 0, stream>>>(QG, KG, SC);
  pe_softmax<<<2048, 256, 0, stream>>>(pe, wg_w, wg_b, SC);
  gemm_final<<<dim3(32, 16), 256, 0, stream>>>(SC, SVT, RS, wv_b, (float*)d_out);
}